// Round 7
// baseline (341.231 us; speedup 1.0000x reference)
//
#include <hip/hip_runtime.h>

// GPT forward, MI355X gfx950. bf16 MFMA, fused MLP (no activation), max-free
// softmax, KV-split XCD-pinned attention, fused per-layer epilogue megakernel
// (combine + proj + MLP + next-qkv). B=4, T=2048, C=256, H=4, D=64, L=4, V=2048.

typedef __attribute__((ext_vector_type(8))) short short8;
typedef __attribute__((ext_vector_type(4))) short short4_t;
typedef __attribute__((ext_vector_type(4))) float f32x4;

static __device__ __forceinline__ short f2bf(float f) {
    unsigned int u = __float_as_uint(f);
    unsigned int r = (u + 0x7FFFu + ((u >> 16) & 1u)) >> 16;  // RNE
    return (short)r;
}

static __device__ __forceinline__ void glds16(const void* g, void* l) {
    __builtin_amdgcn_global_load_lds(
        (const __attribute__((address_space(1))) unsigned int*)g,
        (__attribute__((address_space(3))) unsigned int*)l, 16, 0, 0);
}

// ---------------- embed: x = tok_emb[idx] + pos_emb; also bf16 copy ---------
__global__ __launch_bounds__(256) void embed_kernel(
    const int* __restrict__ idx, const float* __restrict__ tok,
    const float* __restrict__ pos, float* __restrict__ x, short* __restrict__ xb) {
    int i = (blockIdx.x * 256 + threadIdx.x) * 4;
    int row = i >> 8, c = i & 255, t = row & 2047;
    int tr = idx[row];
    float4 a = *(const float4*)(tok + (size_t)tr * 256 + c);
    float4 p = *(const float4*)(pos + (size_t)t * 256 + c);
    float4 o; o.x = a.x + p.x; o.y = a.y + p.y; o.z = a.z + p.z; o.w = a.w + p.w;
    *(float4*)(x + i) = o;
    short4_t s; s.x = f2bf(o.x); s.y = f2bf(o.y); s.z = f2bf(o.z); s.w = f2bf(o.w);
    *(short4_t*)(xb + i) = s;
}

// ---------------- weight prep -----------------------------------------------
__global__ __launch_bounds__(256) void convt_kernel(
    const float* __restrict__ src, short* __restrict__ dst, int R, int C) {
    __shared__ float tile[32][33];
    int bz = blockIdx.z;
    const float* s = src + (size_t)bz * R * C;
    short* d = dst + (size_t)bz * R * C;
    int c0 = blockIdx.x * 32, r0 = blockIdx.y * 32;
    int tx = threadIdx.x & 31, ty = threadIdx.x >> 5;
    #pragma unroll
    for (int i = 0; i < 4; ++i)
        tile[ty + 8 * i][tx] = s[(size_t)(r0 + ty + 8 * i) * C + c0 + tx];
    __syncthreads();
    #pragma unroll
    for (int i = 0; i < 4; ++i)
        d[(size_t)(c0 + ty + 8 * i) * R + r0 + tx] = f2bf(tile[tx][ty + 8 * i]);
}

__global__ __launch_bounds__(256) void convc_kernel(
    const float* __restrict__ src, short* __restrict__ dst) {
    int i = (blockIdx.x * 256 + threadIdx.x) * 8;
    float4 a = *(const float4*)(src + i);
    float4 b = *(const float4*)(src + i + 4);
    short8 o; o[0]=f2bf(a.x); o[1]=f2bf(a.y); o[2]=f2bf(a.z); o[3]=f2bf(a.w);
    o[4]=f2bf(b.x); o[5]=f2bf(b.y); o[6]=f2bf(b.z); o[7]=f2bf(b.w);
    *(short8*)(dst + i) = o;
}

// bmlp[l][n] = sum_k bfc[l][k]*Wfp[l][k][n] + bfp[l][n]  (parallel k-split)
__global__ __launch_bounds__(256) void biasmlp_kernel(
    const float* __restrict__ bfc, const float* __restrict__ wfp,
    const float* __restrict__ bfp, float* __restrict__ bmlp) {
    __shared__ float red[4][64];
    int l = blockIdx.x, ng = blockIdx.y;
    int n_in = threadIdx.x & 63, kk = threadIdx.x >> 6;
    int n = ng * 64 + n_in;
    const float* w = wfp + (size_t)l * 262144 + n;
    const float* bf = bfc + l * 1024;
    float s = 0.0f;
    #pragma unroll 4
    for (int k = kk * 256; k < kk * 256 + 256; ++k)
        s += bf[k] * w[(size_t)k * 256];
    red[kk][n_in] = s;
    __syncthreads();
    if (kk == 0)
        bmlp[l * 256 + n] = red[0][n_in] + red[1][n_in] + red[2][n_in] + red[3][n_in]
                            + bfp[l * 256 + n];
}

// ---------------- bf16 GEMM: A[M,K]bf16 @ Bt[N,K]bf16^T ----------------------
// MODE 1: qkv split -> Qg/Kg bf16 [bh][t][64], Vg bf16 [bh][64][t].
// MODE 2: transposed bf16 out (Wmlp prep), batched via z.
template<int MODE>
__global__ __launch_bounds__(256) void gemmb_kernel(
    const short* __restrict__ A, const short* __restrict__ Bt,
    const float* __restrict__ bias, float* __restrict__ outf,
    short* __restrict__ outb,
    short* __restrict__ qg, short* __restrict__ kg, short* __restrict__ vg,
    int M, int N, int K, int sA, int sB, int sO) {
    __shared__ short Asb[3][4096];
    __shared__ short Bsb[3][4096];
    int tid = threadIdx.x, lane = tid & 63, wid = tid >> 6;
    int lg = lane >> 4, lr = lane & 15;
    int m0 = blockIdx.y * 64, n0 = blockIdx.x * 64;
    const short* Ab = A + (size_t)blockIdx.z * sA;
    const short* Bb = Bt + (size_t)blockIdx.z * sB;
    int wm = (wid >> 1) * 32, wn = (wid & 1) * 32;
    int srow = lane >> 3;
    int gc = (lane & 7) ^ (srow & 7);
    int nt = K >> 6;

    auto stage = [&](int t) {
        int buf = t - (t / 3) * 3;
        int k0 = t << 6;
        #pragma unroll
        for (int o2 = 0; o2 < 2; ++o2) {
            int o = wid * 2 + o2;
            glds16(Ab + (size_t)(m0 + o * 8 + srow) * K + k0 + gc * 8, &Asb[buf][o * 512]);
            glds16(Bb + (size_t)(n0 + o * 8 + srow) * K + k0 + gc * 8, &Bsb[buf][o * 512]);
        }
    };

    f32x4 acc[2][2] = {};
    stage(0);
    if (nt > 1) stage(1);

    for (int t = 0; t < nt; ++t) {
        if (t + 1 < nt) asm volatile("s_waitcnt vmcnt(4)" ::: "memory");
        else            asm volatile("s_waitcnt vmcnt(0)" ::: "memory");
        __builtin_amdgcn_s_barrier();
        if (t + 2 < nt) stage(t + 2);
        int buf = t - (t / 3) * 3;
        short8 af[2][2], bfr[2][2];
        #pragma unroll
        for (int mi = 0; mi < 2; ++mi) {
            int row = wm + mi * 16 + lr;
            #pragma unroll
            for (int h = 0; h < 2; ++h)
                af[mi][h] = *(const short8*)&Asb[buf][row * 64 + ((h * 4 + lg) ^ (lr & 7)) * 8];
        }
        #pragma unroll
        for (int ni = 0; ni < 2; ++ni) {
            int row = wn + ni * 16 + lr;
            #pragma unroll
            for (int h = 0; h < 2; ++h)
                bfr[ni][h] = *(const short8*)&Bsb[buf][row * 64 + ((h * 4 + lg) ^ (lr & 7)) * 8];
        }
        #pragma unroll
        for (int h = 0; h < 2; ++h)
            #pragma unroll
            for (int mi = 0; mi < 2; ++mi)
                #pragma unroll
                for (int ni = 0; ni < 2; ++ni)
                    acc[mi][ni] = __builtin_amdgcn_mfma_f32_16x16x32_bf16(
                        af[mi][h], bfr[ni][h], acc[mi][ni], 0, 0, 0);
    }

    #pragma unroll
    for (int mi = 0; mi < 2; ++mi) {
        #pragma unroll
        for (int ni = 0; ni < 2; ++ni) {
            int col = n0 + wn + ni * 16 + lr;
            if constexpr (MODE == 1) {
                float bv = bias[col];
                int sec = col >> 8, h = (col >> 6) & 3, d = col & 63;
                int rb = m0 + wm + mi * 16 + lg * 4;
                int t2 = rb & 2047, bh = ((rb >> 11) << 2) | h;
                if (sec == 2) {
                    short4_t pk;
                    #pragma unroll
                    for (int r = 0; r < 4; ++r) pk[r] = f2bf(acc[mi][ni][r] + bv);
                    *(short4_t*)&vg[(size_t)bh * 131072 + (size_t)d * 2048 + t2] = pk;
                } else {
                    short* dst = (sec == 0 ? qg : kg) + (size_t)bh * 131072 + (size_t)t2 * 64 + d;
                    #pragma unroll
                    for (int r = 0; r < 4; ++r) dst[r * 64] = f2bf(acc[mi][ni][r] + bv);
                }
            } else {
                #pragma unroll
                for (int r = 0; r < 4; ++r) {
                    int row = m0 + wm + mi * 16 + lg * 4 + r;
                    outb[(size_t)blockIdx.z * sO + (size_t)col * M + row] = f2bf(acc[mi][ni][r]);
                }
            }
        }
    }
    (void)outf;
}

// ---------------- causal flash attention, KV-split, XCD-pinned ---------------
// Always writes raw fp32 O-partials + rowsum partials (max-free => linear).
__global__ __launch_bounds__(256) void attn_kernel(
    const short* __restrict__ qg, const short* __restrict__ kg,
    const short* __restrict__ vg, float* __restrict__ Op, float* __restrict__ rp) {
    __shared__ short Kb[2][4096];
    __shared__ short Vb[2][4096];
    __shared__ short Ps[4][16][72];
    int g = blockIdx.x;
    int idx = g >> 3;
    int bh = (g & 7) * 2 + (idx / 80);
    int i = 79 - (idx % 80);            // heavy chunks dispatch first per XCD
    int qt, s;
    if (i < 8)       { qt = i; s = 0; }
    else if (i < 24) { int j = i - 8;  qt = 8  + (j >> 1); s = j & 1; }
    else if (i < 48) { int j = i - 24; int q3 = j / 3; qt = 16 + q3; s = j - q3 * 3; }
    else             { int j = i - 48; qt = 24 + (j >> 2); s = j & 3; }
    int t0 = s * 8;
    int t1 = min(t0 + 8, qt + 1);
    int q0 = qt << 6;
    int tid = threadIdx.x, lane = tid & 63, wid = tid >> 6;
    int lg = lane >> 4, lr = lane & 15;
    const float scale = 0.125f;
    const size_t base = (size_t)bh << 17;
    int srow = lane >> 3;
    int gc = (lane & 7) ^ (srow & 7);

    const short* qrow = qg + base + (size_t)(q0 + wid * 16 + lr) * 64;
    short8 qf0 = *(const short8*)(qrow + lg * 8);
    short8 qf1 = *(const short8*)(qrow + 32 + lg * 8);

    auto stage = [&](int t) {
        int buf = (t - t0) & 1;
        #pragma unroll
        for (int o2 = 0; o2 < 2; ++o2) {
            int o = wid * 2 + o2;
            glds16(kg + base + (size_t)(t * 64 + o * 8 + srow) * 64 + gc * 8, &Kb[buf][o * 512]);
            glds16(vg + base + (size_t)(o * 8 + srow) * 2048 + t * 64 + gc * 8, &Vb[buf][o * 512]);
        }
    };

    f32x4 o[4] = {};
    float rs = 0.0f;
    stage(t0);
    if (t0 + 1 < t1) stage(t0 + 1);

    for (int j = t0; j < t1; ++j) {
        if (j + 1 < t1) asm volatile("s_waitcnt vmcnt(4)" ::: "memory");
        else            asm volatile("s_waitcnt vmcnt(0)" ::: "memory");
        __builtin_amdgcn_s_barrier();
        int buf = (j - t0) & 1;

        f32x4 sv[4];
        #pragma unroll
        for (int nf = 0; nf < 4; ++nf) {
            int row = nf * 16 + lr;
            short8 k0f = *(const short8*)&Kb[buf][row * 64 + ((0 + lg) ^ (lr & 7)) * 8];
            short8 k1f = *(const short8*)&Kb[buf][row * 64 + ((4 + lg) ^ (lr & 7)) * 8];
            f32x4 z = {};
            z = __builtin_amdgcn_mfma_f32_16x16x32_bf16(k0f, qf0, z, 0, 0, 0);
            z = __builtin_amdgcn_mfma_f32_16x16x32_bf16(k1f, qf1, z, 0, 0, 0);
            sv[nf] = z;
        }
        bool diag = (j == qt);
        #pragma unroll
        for (int nf = 0; nf < 4; ++nf) {
            short4_t p4;
            #pragma unroll
            for (int r = 0; r < 4; ++r) {
                float v = sv[nf][r] * scale;
                if (diag && (nf * 16 + lg * 4 + r > wid * 16 + lr)) v = -3e38f;
                float pe = __expf(v);
                rs += pe;
                p4[r] = f2bf(pe);
            }
            *(short4_t*)&Ps[wid][lr][nf * 16 + lg * 4] = p4;
        }
        short8 pf0 = *(const short8*)&Ps[wid][lr][lg * 8];
        short8 pf1 = *(const short8*)&Ps[wid][lr][32 + lg * 8];
        #pragma unroll
        for (int df = 0; df < 4; ++df) {
            int row = df * 16 + lr;
            short8 v0 = *(const short8*)&Vb[buf][row * 64 + ((0 + lg) ^ (lr & 7)) * 8];
            short8 v1 = *(const short8*)&Vb[buf][row * 64 + ((4 + lg) ^ (lr & 7)) * 8];
            o[df] = __builtin_amdgcn_mfma_f32_16x16x32_bf16(pf0, v0, o[df], 0, 0, 0);
            o[df] = __builtin_amdgcn_mfma_f32_16x16x32_bf16(pf1, v1, o[df], 0, 0, 0);
        }
        __builtin_amdgcn_s_barrier();
        if (j + 2 < t1) stage(j + 2);
    }

    rs += __shfl_xor(rs, 16);
    rs += __shfl_xor(rs, 32);

    int slab = (bh * 32 + qt) * 4 + s;
    float* ob = Op + (size_t)slab * 4096;
    #pragma unroll
    for (int df = 0; df < 4; ++df)
        #pragma unroll
        for (int r = 0; r < 4; ++r)
            ob[(wid * 16 + lg * 4 + r) * 64 + df * 16 + lr] = o[df][r];
    if (lane < 16) rp[slab * 64 + wid * 16 + lane] = rs;
}

// ---------------- fused layer epilogue: combine + proj + MLP + next qkv ------
// 512 threads (8 waves), 32 rows/block, grid 256. Wave w: rows (w&1)*16,
// cols (w>>1)*64 (4 16-col frags). A-operands (y, x1, x2) cycle through one
// swizzled LDS buffer al[4 heads][32 rows][64]; B-operands read direct from L2.
__global__ __launch_bounds__(512) void layer_kernel(
    const float* __restrict__ Op, const float* __restrict__ rp,
    float* __restrict__ xg,
    const short* __restrict__ wo, const float* __restrict__ bo,
    const short* __restrict__ wmlp, const float* __restrict__ bmlp,
    const short* __restrict__ wqkv, const float* __restrict__ bqkv,
    short* __restrict__ qg, short* __restrict__ kg, short* __restrict__ vg) {
    __shared__ short al[4][32][64];
    int tid = threadIdx.x, lane = tid & 63, wid = tid >> 6;
    int lg = (lane >> 4) & 3, lr = lane & 15;
    int r0 = blockIdx.x * 32;
    int b = r0 >> 11, qt = (r0 & 2047) >> 6;
    int rowIn0 = r0 & 32;               // half of the 64-row qt tile
    int ns = (qt >> 3) + 1;
    int wr = (wid & 1) * 16, wc = (wid >> 1) * 64;

    // ---- phase 0: combine partials -> y bf16 in LDS ----
    {
        int row = tid >> 4, seg = tid & 15;
        int h = seg >> 2, d0 = (seg & 3) * 16;
        int slab0 = ((b * 4 + h) * 32 + qt) * 4;
        float a[16] = {};
        float rtot = 0.0f;
        for (int s = 0; s < ns; ++s) {
            const float* op = Op + (size_t)(slab0 + s) * 4096 + (rowIn0 + row) * 64 + d0;
            #pragma unroll
            for (int i2 = 0; i2 < 4; ++i2) {
                float4 v = *(const float4*)(op + i2 * 4);
                a[i2*4+0] += v.x; a[i2*4+1] += v.y; a[i2*4+2] += v.z; a[i2*4+3] += v.w;
            }
            rtot += rp[(slab0 + s) * 64 + rowIn0 + row];
        }
        float inv = 1.0f / rtot;
        short8 o0, o1;
        #pragma unroll
        for (int i2 = 0; i2 < 8; ++i2) { o0[i2] = f2bf(a[i2] * inv); o1[i2] = f2bf(a[8 + i2] * inv); }
        int c0 = d0 >> 3;
        *(short8*)&al[h][row][((c0) ^ (row & 7)) * 8] = o0;
        *(short8*)&al[h][row][((c0 + 1) ^ (row & 7)) * 8] = o1;
    }
    __syncthreads();

    // GEMM over LDS A (32 rows) x global B^T [256 n][256 k], wave frags f=0..3
    auto gemmphase = [&](const short* Bt, f32x4* acc) {
        #pragma unroll
        for (int ks = 0; ks < 8; ++ks) {
            short8 a = *(const short8*)&al[ks >> 1][wr + lr][((((ks & 1) << 2) + lg) ^ (lr & 7)) * 8];
            #pragma unroll
            for (int f = 0; f < 4; ++f) {
                short8 bfrag = *(const short8*)(Bt + (size_t)(wc + f * 16 + lr) * 256 + ks * 32 + lg * 8);
                acc[f] = __builtin_amdgcn_mfma_f32_16x16x32_bf16(a, bfrag, acc[f], 0, 0, 0);
            }
        }
    };
    // write a thread's 4x4 fp32 frags as bf16 into al (same swizzle)
    auto store_a = [&](f32x4* v) {
        #pragma unroll
        for (int f = 0; f < 4; ++f) {
            int col = wc + f * 16 + lr;
            int h2 = col >> 6, ch = (col & 63) >> 3, pos = col & 7;
            #pragma unroll
            for (int rr = 0; rr < 4; ++rr) {
                int row = wr + lg * 4 + rr;
                al[h2][row][(ch ^ (row & 7)) * 8 + pos] = f2bf(v[f][rr]);
            }
        }
    };

    // ---- phase 1: x1 = x + y@Wo + bo ----
    f32x4 acc1[4] = {};
    gemmphase(wo, acc1);
    f32x4 x1[4];
    #pragma unroll
    for (int f = 0; f < 4; ++f) {
        int col = wc + f * 16 + lr;
        float bv = bo[col];
        #pragma unroll
        for (int rr = 0; rr < 4; ++rr) {
            int row = r0 + wr + lg * 4 + rr;
            x1[f][rr] = acc1[f][rr] + bv + xg[(size_t)row * 256 + col];
        }
    }
    __syncthreads();
    store_a(x1);
    __syncthreads();

    // ---- phase 2: x2 = x1 + x1@Wmlp + bmlp ----
    f32x4 acc2[4] = {};
    gemmphase(wmlp, acc2);
    f32x4 x2[4];
    #pragma unroll
    for (int f = 0; f < 4; ++f) {
        int col = wc + f * 16 + lr;
        float bv = bmlp[col];
        #pragma unroll
        for (int rr = 0; rr < 4; ++rr) {
            int row = r0 + wr + lg * 4 + rr;
            float v = x1[f][rr] + acc2[f][rr] + bv;
            x2[f][rr] = v;
            xg[(size_t)row * 256 + col] = v;
        }
    }
    if (!qg) return;                    // last layer: head reads xg fp32
    __syncthreads();
    store_a(x2);
    __syncthreads();

    // ---- phase 3: qkv(next) = x2@Wqkv + bqkv, split-scattered ----
    #pragma unroll
    for (int nc = 0; nc < 3; ++nc) {
        f32x4 acc3[4] = {};
        gemmphase(wqkv + (size_t)nc * 65536, acc3);
        #pragma unroll
        for (int f = 0; f < 4; ++f) {
            int col = wc + f * 16 + lr;
            float bv = bqkv[nc * 256 + col];
            int h2 = col >> 6, d = col & 63;
            int bh = b * 4 + h2;
            int t2 = (r0 & 2047) + wr + lg * 4;
            if (nc == 2) {
                short4_t pk;
                #pragma unroll
                for (int rr = 0; rr < 4; ++rr) pk[rr] = f2bf(acc3[f][rr] + bv);
                *(short4_t*)&vg[(size_t)bh * 131072 + (size_t)d * 2048 + t2] = pk;
            } else {
                short* dst = (nc == 0 ? qg : kg) + (size_t)bh * 131072 + (size_t)t2 * 64 + d;
                #pragma unroll
                for (int rr = 0; rr < 4; ++rr) dst[rr * 64] = f2bf(acc3[f][rr] + bv);
            }
        }
    }
}

// ---------------- fp32-input GEMM for the head ------------------------------
__global__ __launch_bounds__(256) void gemm32_kernel(
    const float* __restrict__ A, const float* __restrict__ W,
    float* __restrict__ out, int M, int N, int K) {
    __shared__ short As[2][64][40];
    __shared__ short Bs[2][64][40];
    int tid = threadIdx.x, lane = tid & 63, wid = tid >> 6;
    int lg = lane >> 4, lr = lane & 15;
    int m0 = blockIdx.y * 64, n0 = blockIdx.x * 64;
    int wm = (wid >> 1) * 32, wn = (wid & 1) * 32;
    f32x4 acc[2][2] = {};
    int nt = K >> 5;
    float4 pa0, pa1;
    float pb[8];
    int ar = tid >> 3, ac4 = (tid & 7) * 4;
    int bn = tid & 63, bk8 = (tid >> 6) * 8;
    auto gload = [&](int k0) {
        pa0 = *(const float4*)(A + (size_t)(m0 + ar) * K + k0 + ac4);
        pa1 = *(const float4*)(A + (size_t)(m0 + ar + 32) * K + k0 + ac4);
        #pragma unroll
        for (int j = 0; j < 8; ++j) pb[j] = W[(size_t)(k0 + bk8 + j) * N + n0 + bn];
    };
    auto sstore = [&](int buf) {
        short4_t s0; s0.x=f2bf(pa0.x); s0.y=f2bf(pa0.y); s0.z=f2bf(pa0.z); s0.w=f2bf(pa0.w);
        *(short4_t*)&As[buf][ar][ac4] = s0;
        short4_t s1; s1.x=f2bf(pa1.x); s1.y=f2bf(pa1.y); s1.z=f2bf(pa1.z); s1.w=f2bf(pa1.w);
        *(short4_t*)&As[buf][ar + 32][ac4] = s1;
        short8 bb;
        #pragma unroll
        for (int j = 0; j < 8; ++j) bb[j] = f2bf(pb[j]);
        *(short8*)&Bs[buf][bn][bk8] = bb;
    };
    gload(0); sstore(0); __syncthreads();
    for (int t = 0; t < nt; ++t) {
        if (t + 1 < nt) gload((t + 1) << 5);
        int cur = t & 1;
        short8 af[2], bfr[2];
        af[0]  = *(const short8*)&As[cur][wm + lr][lg * 8];
        af[1]  = *(const short8*)&As[cur][wm + 16 + lr][lg * 8];
        bfr[0] = *(const short8*)&Bs[cur][wn + lr][lg * 8];
        bfr[1] = *(const short8*)&Bs[cur][wn + 16 + lr][lg * 8];
        #pragma unroll
        for (int mi = 0; mi < 2; ++mi)
            #pragma unroll
            for (int ni = 0; ni < 2; ++ni)
                acc[mi][ni] = __builtin_amdgcn_mfma_f32_16x16x32_bf16(
                    af[mi], bfr[ni], acc[mi][ni], 0, 0, 0);
        if (t + 1 < nt) sstore((t + 1) & 1);
        __syncthreads();
    }
    #pragma unroll
    for (int mi = 0; mi < 2; ++mi)
        #pragma unroll
        for (int ni = 0; ni < 2; ++ni) {
            int col = n0 + wn + ni * 16 + lr;
            #pragma unroll
            for (int r = 0; r < 4; ++r) {
                int row = m0 + wm + mi * 16 + lg * 4 + r;
                __builtin_nontemporal_store(acc[mi][ni][r], &out[(size_t)row * N + col]);
            }
        }
}

// ---------------------------------------------------------------------------
extern "C" void kernel_launch(void* const* d_in, const int* in_sizes, int n_in,
                              void* d_out, int out_size, void* d_ws, size_t ws_size,
                              hipStream_t stream) {
    (void)in_sizes; (void)n_in; (void)out_size; (void)ws_size;
    const int*   idx   = (const int*)  d_in[0];
    const float* tok   = (const float*)d_in[1];
    const float* pos   = (const float*)d_in[2];
    const float* Wqkv  = (const float*)d_in[3];
    const float* bqkv  = (const float*)d_in[4];
    const float* Wo    = (const float*)d_in[5];
    const float* bo    = (const float*)d_in[6];
    const float* Wfc   = (const float*)d_in[7];
    const float* bfc   = (const float*)d_in[8];
    const float* Wfp   = (const float*)d_in[9];
    const float* bfp   = (const float*)d_in[10];
    const float* Whead = (const float*)d_in[11];

    float* out = (float*)d_out;
    float* x   = (float*)d_ws;                    // fp32 [8192][256] (8 MB)

    // d_out scratch (16.78M floats; all consumed before head GEMM writes out):
    float* Opart  = out;                          // [2048 slabs][4096] = 8388608
    short* wqkv_t = (short*)(out + 8388608);      // [4][768][256]
    short* wo_t   = wqkv_t + 786432;              // [4][256][256]
    short* wfc_b  = wo_t + 262144;                // [4][256][1024]
    short* wfp_t  = wfc_b + 1048576;              // [4][256][1024]
    short* wmlp_t = wfp_t + 1048576;              // [4][256][256]
    float* bmlp   = (float*)(wmlp_t + 262144);    // [4][256]  ends 10093568
    float* rspart = out + 10093568;               // [2048 slabs][64] = 131072
    short* qgp = (short*)(out + 10485760);        // [16][2048][64]
    short* kgp = qgp + 2097152;
    short* vgp = kgp + 2097152;                   // [16][64][2048]
    short* xb0 = vgp + 2097152;                   // [8192][256] bf16 (embed out)

    // weight prep (deterministic, every call)
    convt_kernel<<<dim3(24, 8, 4), 256, 0, stream>>>(Wqkv, wqkv_t, 256, 768);
    convt_kernel<<<dim3(8, 8, 4), 256, 0, stream>>>(Wo, wo_t, 256, 256);
    convt_kernel<<<dim3(8, 32, 4), 256, 0, stream>>>(Wfp, wfp_t, 1024, 256);
    convc_kernel<<<512, 256, 0, stream>>>(Wfc, wfc_b);
    biasmlp_kernel<<<dim3(4, 4), 256, 0, stream>>>(bfc, Wfp, bfp, bmlp);
    gemmb_kernel<2><<<dim3(4, 4, 4), 256, 0, stream>>>(
        wfc_b, wfp_t, nullptr, nullptr, wmlp_t, nullptr, nullptr, nullptr,
        256, 256, 1024, 262144, 262144, 65536);

    embed_kernel<<<2048, 256, 0, stream>>>(idx, tok, pos, x, xb0);

    // qkv for layer 0
    gemmb_kernel<1><<<dim3(12, 128), 256, 0, stream>>>(
        xb0, wqkv_t, bqkv, nullptr, nullptr, qgp, kgp, vgp,
        8192, 768, 256, 0, 0, 0);

    for (int l = 0; l < 4; ++l) {
        attn_kernel<<<1280, 256, 0, stream>>>(qgp, kgp, vgp, Opart, rspart);
        bool last = (l == 3);
        layer_kernel<<<256, 512, 0, stream>>>(
            Opart, rspart, x,
            wo_t + l * 65536, bo + l * 256,
            wmlp_t + l * 65536, bmlp + l * 256,
            last ? nullptr : (wqkv_t + (l + 1) * 196608),
            last ? nullptr : (bqkv + (l + 1) * 768),
            last ? nullptr : qgp, last ? nullptr : kgp, last ? nullptr : vgp);
    }
    gemm32_kernel<<<dim3(32, 128), 256, 0, stream>>>(x, Whead, out, 8192, 2048, 256);
}

// Round 8
// 264.272 us; speedup vs baseline: 1.2912x; 1.2912x over previous
//
#include <hip/hip_runtime.h>

// GPT forward, MI355X gfx950. bf16 MFMA, fused MLP (no activation), max-free
// softmax, KV-split XCD-pinned attention, fused per-layer megakernel with
// LDS-staged weights. B=4, T=2048, C=256, H=4, D=64, L=4, V=2048.

typedef __attribute__((ext_vector_type(8))) short short8;
typedef __attribute__((ext_vector_type(4))) short short4_t;
typedef __attribute__((ext_vector_type(4))) float f32x4;

static __device__ __forceinline__ short f2bf(float f) {
    unsigned int u = __float_as_uint(f);
    unsigned int r = (u + 0x7FFFu + ((u >> 16) & 1u)) >> 16;  // RNE
    return (short)r;
}

static __device__ __forceinline__ void glds16(const void* g, void* l) {
    __builtin_amdgcn_global_load_lds(
        (const __attribute__((address_space(1))) unsigned int*)g,
        (__attribute__((address_space(3))) unsigned int*)l, 16, 0, 0);
}

// ---------------- embed: x = tok_emb[idx] + pos_emb; also bf16 copy ---------
__global__ __launch_bounds__(256) void embed_kernel(
    const int* __restrict__ idx, const float* __restrict__ tok,
    const float* __restrict__ pos, float* __restrict__ x, short* __restrict__ xb) {
    int i = (blockIdx.x * 256 + threadIdx.x) * 4;
    int row = i >> 8, c = i & 255, t = row & 2047;
    int tr = idx[row];
    float4 a = *(const float4*)(tok + (size_t)tr * 256 + c);
    float4 p = *(const float4*)(pos + (size_t)t * 256 + c);
    float4 o; o.x = a.x + p.x; o.y = a.y + p.y; o.z = a.z + p.z; o.w = a.w + p.w;
    *(float4*)(x + i) = o;
    short4_t s; s.x = f2bf(o.x); s.y = f2bf(o.y); s.z = f2bf(o.z); s.w = f2bf(o.w);
    *(short4_t*)(xb + i) = s;
}

// ---------------- weight prep -----------------------------------------------
__global__ __launch_bounds__(256) void convt_kernel(
    const float* __restrict__ src, short* __restrict__ dst, int R, int C) {
    __shared__ float tile[32][33];
    int bz = blockIdx.z;
    const float* s = src + (size_t)bz * R * C;
    short* d = dst + (size_t)bz * R * C;
    int c0 = blockIdx.x * 32, r0 = blockIdx.y * 32;
    int tx = threadIdx.x & 31, ty = threadIdx.x >> 5;
    #pragma unroll
    for (int i = 0; i < 4; ++i)
        tile[ty + 8 * i][tx] = s[(size_t)(r0 + ty + 8 * i) * C + c0 + tx];
    __syncthreads();
    #pragma unroll
    for (int i = 0; i < 4; ++i)
        d[(size_t)(c0 + ty + 8 * i) * R + r0 + tx] = f2bf(tile[tx][ty + 8 * i]);
}

__global__ __launch_bounds__(256) void convc_kernel(
    const float* __restrict__ src, short* __restrict__ dst) {
    int i = (blockIdx.x * 256 + threadIdx.x) * 8;
    float4 a = *(const float4*)(src + i);
    float4 b = *(const float4*)(src + i + 4);
    short8 o; o[0]=f2bf(a.x); o[1]=f2bf(a.y); o[2]=f2bf(a.z); o[3]=f2bf(a.w);
    o[4]=f2bf(b.x); o[5]=f2bf(b.y); o[6]=f2bf(b.z); o[7]=f2bf(b.w);
    *(short8*)(dst + i) = o;
}

// bmlp[l][n] = sum_k bfc[l][k]*Wfp[l][k][n] + bfp[l][n]  (parallel k-split)
__global__ __launch_bounds__(256) void biasmlp_kernel(
    const float* __restrict__ bfc, const float* __restrict__ wfp,
    const float* __restrict__ bfp, float* __restrict__ bmlp) {
    __shared__ float red[4][64];
    int l = blockIdx.x, ng = blockIdx.y;
    int n_in = threadIdx.x & 63, kk = threadIdx.x >> 6;
    int n = ng * 64 + n_in;
    const float* w = wfp + (size_t)l * 262144 + n;
    const float* bf = bfc + l * 1024;
    float s = 0.0f;
    #pragma unroll 4
    for (int k = kk * 256; k < kk * 256 + 256; ++k)
        s += bf[k] * w[(size_t)k * 256];
    red[kk][n_in] = s;
    __syncthreads();
    if (kk == 0)
        bmlp[l * 256 + n] = red[0][n_in] + red[1][n_in] + red[2][n_in] + red[3][n_in]
                            + bfp[l * 256 + n];
}

// ---------------- bf16 GEMM: A[M,K]bf16 @ Bt[N,K]bf16^T ----------------------
// MODE 1: qkv split -> Qg/Kg bf16 [bh][t][64], Vg bf16 [bh][64][t].
// MODE 2: transposed bf16 out (Wmlp prep), batched via z.
template<int MODE>
__global__ __launch_bounds__(256) void gemmb_kernel(
    const short* __restrict__ A, const short* __restrict__ Bt,
    const float* __restrict__ bias, float* __restrict__ outf,
    short* __restrict__ outb,
    short* __restrict__ qg, short* __restrict__ kg, short* __restrict__ vg,
    int M, int N, int K, int sA, int sB, int sO) {
    __shared__ short Asb[3][4096];
    __shared__ short Bsb[3][4096];
    int tid = threadIdx.x, lane = tid & 63, wid = tid >> 6;
    int lg = lane >> 4, lr = lane & 15;
    int m0 = blockIdx.y * 64, n0 = blockIdx.x * 64;
    const short* Ab = A + (size_t)blockIdx.z * sA;
    const short* Bb = Bt + (size_t)blockIdx.z * sB;
    int wm = (wid >> 1) * 32, wn = (wid & 1) * 32;
    int srow = lane >> 3;
    int gc = (lane & 7) ^ (srow & 7);
    int nt = K >> 6;

    auto stage = [&](int t) {
        int buf = t - (t / 3) * 3;
        int k0 = t << 6;
        #pragma unroll
        for (int o2 = 0; o2 < 2; ++o2) {
            int o = wid * 2 + o2;
            glds16(Ab + (size_t)(m0 + o * 8 + srow) * K + k0 + gc * 8, &Asb[buf][o * 512]);
            glds16(Bb + (size_t)(n0 + o * 8 + srow) * K + k0 + gc * 8, &Bsb[buf][o * 512]);
        }
    };

    f32x4 acc[2][2] = {};
    stage(0);
    if (nt > 1) stage(1);

    for (int t = 0; t < nt; ++t) {
        if (t + 1 < nt) asm volatile("s_waitcnt vmcnt(4)" ::: "memory");
        else            asm volatile("s_waitcnt vmcnt(0)" ::: "memory");
        __builtin_amdgcn_s_barrier();
        if (t + 2 < nt) stage(t + 2);
        int buf = t - (t / 3) * 3;
        short8 af[2][2], bfr[2][2];
        #pragma unroll
        for (int mi = 0; mi < 2; ++mi) {
            int row = wm + mi * 16 + lr;
            #pragma unroll
            for (int h = 0; h < 2; ++h)
                af[mi][h] = *(const short8*)&Asb[buf][row * 64 + ((h * 4 + lg) ^ (lr & 7)) * 8];
        }
        #pragma unroll
        for (int ni = 0; ni < 2; ++ni) {
            int row = wn + ni * 16 + lr;
            #pragma unroll
            for (int h = 0; h < 2; ++h)
                bfr[ni][h] = *(const short8*)&Bsb[buf][row * 64 + ((h * 4 + lg) ^ (lr & 7)) * 8];
        }
        #pragma unroll
        for (int h = 0; h < 2; ++h)
            #pragma unroll
            for (int mi = 0; mi < 2; ++mi)
                #pragma unroll
                for (int ni = 0; ni < 2; ++ni)
                    acc[mi][ni] = __builtin_amdgcn_mfma_f32_16x16x32_bf16(
                        af[mi][h], bfr[ni][h], acc[mi][ni], 0, 0, 0);
    }

    #pragma unroll
    for (int mi = 0; mi < 2; ++mi) {
        #pragma unroll
        for (int ni = 0; ni < 2; ++ni) {
            int col = n0 + wn + ni * 16 + lr;
            if constexpr (MODE == 1) {
                float bv = bias[col];
                int sec = col >> 8, h = (col >> 6) & 3, d = col & 63;
                int rb = m0 + wm + mi * 16 + lg * 4;
                int t2 = rb & 2047, bh = ((rb >> 11) << 2) | h;
                if (sec == 2) {
                    short4_t pk;
                    #pragma unroll
                    for (int r = 0; r < 4; ++r) pk[r] = f2bf(acc[mi][ni][r] + bv);
                    *(short4_t*)&vg[(size_t)bh * 131072 + (size_t)d * 2048 + t2] = pk;
                } else {
                    short* dst = (sec == 0 ? qg : kg) + (size_t)bh * 131072 + (size_t)t2 * 64 + d;
                    #pragma unroll
                    for (int r = 0; r < 4; ++r) dst[r * 64] = f2bf(acc[mi][ni][r] + bv);
                }
            } else {
                #pragma unroll
                for (int r = 0; r < 4; ++r) {
                    int row = m0 + wm + mi * 16 + lg * 4 + r;
                    outb[(size_t)blockIdx.z * sO + (size_t)col * M + row] = f2bf(acc[mi][ni][r]);
                }
            }
        }
    }
    (void)outf;
}

// ---------------- causal flash attention, KV-split, XCD-pinned ---------------
__global__ __launch_bounds__(256) void attn_kernel(
    const short* __restrict__ qg, const short* __restrict__ kg,
    const short* __restrict__ vg, float* __restrict__ Op, float* __restrict__ rp) {
    __shared__ short Kb[2][4096];
    __shared__ short Vb[2][4096];
    __shared__ short Ps[4][16][72];
    int g = blockIdx.x;
    int idx = g >> 3;
    int bh = (g & 7) * 2 + (idx / 80);
    int i = 79 - (idx % 80);
    int qt, s;
    if (i < 8)       { qt = i; s = 0; }
    else if (i < 24) { int j = i - 8;  qt = 8  + (j >> 1); s = j & 1; }
    else if (i < 48) { int j = i - 24; int q3 = j / 3; qt = 16 + q3; s = j - q3 * 3; }
    else             { int j = i - 48; qt = 24 + (j >> 2); s = j & 3; }
    int t0 = s * 8;
    int t1 = min(t0 + 8, qt + 1);
    int q0 = qt << 6;
    int tid = threadIdx.x, lane = tid & 63, wid = tid >> 6;
    int lg = lane >> 4, lr = lane & 15;
    const float scale = 0.125f;
    const size_t base = (size_t)bh << 17;
    int srow = lane >> 3;
    int gc = (lane & 7) ^ (srow & 7);

    const short* qrow = qg + base + (size_t)(q0 + wid * 16 + lr) * 64;
    short8 qf0 = *(const short8*)(qrow + lg * 8);
    short8 qf1 = *(const short8*)(qrow + 32 + lg * 8);

    auto stage = [&](int t) {
        int buf = (t - t0) & 1;
        #pragma unroll
        for (int o2 = 0; o2 < 2; ++o2) {
            int o = wid * 2 + o2;
            glds16(kg + base + (size_t)(t * 64 + o * 8 + srow) * 64 + gc * 8, &Kb[buf][o * 512]);
            glds16(vg + base + (size_t)(o * 8 + srow) * 2048 + t * 64 + gc * 8, &Vb[buf][o * 512]);
        }
    };

    f32x4 o[4] = {};
    float rs = 0.0f;
    stage(t0);
    if (t0 + 1 < t1) stage(t0 + 1);

    for (int j = t0; j < t1; ++j) {
        if (j + 1 < t1) asm volatile("s_waitcnt vmcnt(4)" ::: "memory");
        else            asm volatile("s_waitcnt vmcnt(0)" ::: "memory");
        __builtin_amdgcn_s_barrier();
        int buf = (j - t0) & 1;

        f32x4 sv[4];
        #pragma unroll
        for (int nf = 0; nf < 4; ++nf) {
            int row = nf * 16 + lr;
            short8 k0f = *(const short8*)&Kb[buf][row * 64 + ((0 + lg) ^ (lr & 7)) * 8];
            short8 k1f = *(const short8*)&Kb[buf][row * 64 + ((4 + lg) ^ (lr & 7)) * 8];
            f32x4 z = {};
            z = __builtin_amdgcn_mfma_f32_16x16x32_bf16(k0f, qf0, z, 0, 0, 0);
            z = __builtin_amdgcn_mfma_f32_16x16x32_bf16(k1f, qf1, z, 0, 0, 0);
            sv[nf] = z;
        }
        bool diag = (j == qt);
        #pragma unroll
        for (int nf = 0; nf < 4; ++nf) {
            short4_t p4;
            #pragma unroll
            for (int r = 0; r < 4; ++r) {
                float v = sv[nf][r] * scale;
                if (diag && (nf * 16 + lg * 4 + r > wid * 16 + lr)) v = -3e38f;
                float pe = __expf(v);
                rs += pe;
                p4[r] = f2bf(pe);
            }
            *(short4_t*)&Ps[wid][lr][nf * 16 + lg * 4] = p4;
        }
        short8 pf0 = *(const short8*)&Ps[wid][lr][lg * 8];
        short8 pf1 = *(const short8*)&Ps[wid][lr][32 + lg * 8];
        #pragma unroll
        for (int df = 0; df < 4; ++df) {
            int row = df * 16 + lr;
            short8 v0 = *(const short8*)&Vb[buf][row * 64 + ((0 + lg) ^ (lr & 7)) * 8];
            short8 v1 = *(const short8*)&Vb[buf][row * 64 + ((4 + lg) ^ (lr & 7)) * 8];
            o[df] = __builtin_amdgcn_mfma_f32_16x16x32_bf16(pf0, v0, o[df], 0, 0, 0);
            o[df] = __builtin_amdgcn_mfma_f32_16x16x32_bf16(pf1, v1, o[df], 0, 0, 0);
        }
        __builtin_amdgcn_s_barrier();
        if (j + 2 < t1) stage(j + 2);
    }

    rs += __shfl_xor(rs, 16);
    rs += __shfl_xor(rs, 32);

    int slab = (bh * 32 + qt) * 4 + s;
    float* ob = Op + (size_t)slab * 4096;
    #pragma unroll
    for (int df = 0; df < 4; ++df)
        #pragma unroll
        for (int r = 0; r < 4; ++r)
            ob[(wid * 16 + lg * 4 + r) * 64 + df * 16 + lr] = o[df][r];
    if (lane < 16) rp[slab * 64 + wid * 16 + lane] = rs;
}

// ---------------- fused layer: combine + proj + MLP + next qkv ---------------
// 512 threads, 32 rows/block, grid 256 (= CU count). A-operands in al (16 KB);
// weights LDS-staged in 2x64 KB half-K buffers via glds16 (pre-swizzled source,
// chunk^= n&15), counted vmcnt(8), raw barriers. 5 phases x 2 halves = 10 steps.
__global__ __launch_bounds__(512) void layer_kernel(
    const float* __restrict__ Op, const float* __restrict__ rp,
    float* __restrict__ xg,
    const short* __restrict__ wo, const float* __restrict__ bo,
    const short* __restrict__ wmlp, const float* __restrict__ bmlp,
    const short* __restrict__ wqkv, const float* __restrict__ bqkv,
    short* __restrict__ qg, short* __restrict__ kg, short* __restrict__ vg) {
    __shared__ short al[4][32][64];      // 16 KB (A operand, swizzled)
    __shared__ short wl[2][32768];       // 2 x 64 KB (weight half-K buffers)
    int tid = threadIdx.x, lane = tid & 63, wid = tid >> 6;
    int lg = (lane >> 4) & 3, lr = lane & 15;
    int r0 = blockIdx.x * 32;
    int b = r0 >> 11, qt = (r0 & 2047) >> 6;
    int rowIn0 = r0 & 32;
    int ns = (qt >> 3) + 1;
    int wr = (wid & 1) * 16, wc = (wid >> 1) * 64;

    const short* wlist[5];
    wlist[0] = wo; wlist[1] = wmlp; wlist[2] = wqkv;
    wlist[3] = wqkv ? wqkv + 65536 : wo; wlist[4] = wqkv ? wqkv + 131072 : wo;
    int nsteps = qg ? 10 : 4;

    // ---- combine partials -> y bf16 in al ----
    {
        int row = tid >> 4, seg = tid & 15;
        int h = seg >> 2, d0 = (seg & 3) * 16;
        int slab0 = ((b * 4 + h) * 32 + qt) * 4;
        float a[16] = {};
        float rtot = 0.0f;
        for (int s = 0; s < ns; ++s) {
            const float* op = Op + (size_t)(slab0 + s) * 4096 + (rowIn0 + row) * 64 + d0;
            #pragma unroll
            for (int i2 = 0; i2 < 4; ++i2) {
                float4 v = *(const float4*)(op + i2 * 4);
                a[i2*4+0] += v.x; a[i2*4+1] += v.y; a[i2*4+2] += v.z; a[i2*4+3] += v.w;
            }
            rtot += rp[(slab0 + s) * 64 + rowIn0 + row];
        }
        float inv = 1.0f / rtot;
        short8 o0, o1;
        #pragma unroll
        for (int i2 = 0; i2 < 8; ++i2) { o0[i2] = f2bf(a[i2] * inv); o1[i2] = f2bf(a[8 + i2] * inv); }
        int c0 = d0 >> 3;
        *(short8*)&al[h][row][((c0) ^ (row & 7)) * 8] = o0;
        *(short8*)&al[h][row][((c0 + 1) ^ (row & 7)) * 8] = o1;
    }

    // stage weight half: step s -> phase s>>1, half s&1, buffer wl[s&1].
    // LDS layout: [n][16 chunks of 8 shorts], stored chunk_lin holds global
    // chunk (chunk_lin ^ (n&15)) -> read with chunk ^ (n&15) (2-way free).
    auto stage_w = [&](int s) {
        const short* wt = wlist[s >> 1];
        int h = s & 1;
        short* dst = wl[h];
        int n_l = lane >> 4, cl = lane & 15;
        #pragma unroll
        for (int c4 = 0; c4 < 8; ++c4) {
            int n0 = wid * 32 + c4 * 4;
            int n = n0 + n_l;
            glds16(wt + (size_t)n * 256 + h * 128 + (cl ^ (n & 15)) * 8,
                   dst + n0 * 128);
        }
    };
    // write a thread's 4x4 fp32 frags as bf16 into al (same swizzle as combine)
    auto store_a = [&](f32x4* v) {
        #pragma unroll
        for (int f = 0; f < 4; ++f) {
            int col = wc + f * 16 + lr;
            int h2 = col >> 6, ch = (col & 63) >> 3, pos = col & 7;
            #pragma unroll
            for (int rr = 0; rr < 4; ++rr) {
                int row = wr + lg * 4 + rr;
                al[h2][row][(ch ^ (row & 7)) * 8 + pos] = f2bf(v[f][rr]);
            }
        }
    };

    stage_w(0);
    stage_w(1);
    asm volatile("s_waitcnt lgkmcnt(0)" ::: "memory");   // al writes visible
    __builtin_amdgcn_s_barrier();

    f32x4 acc[4] = {};
    f32x4 x1[4], x2[4];

    for (int s = 0; s < nsteps; ++s) {
        if (s == nsteps - 1) asm volatile("s_waitcnt vmcnt(0)" ::: "memory");
        else                 asm volatile("s_waitcnt vmcnt(8)" ::: "memory");
        __builtin_amdgcn_s_barrier();
        int h = s & 1, p = s >> 1;
        const short* wb = wl[h];
        #pragma unroll
        for (int s2 = 0; s2 < 4; ++s2) {
            int ksg = h * 4 + s2;
            short8 a = *(const short8*)&al[ksg >> 1][wr + lr][((((ksg & 1) << 2) + lg) ^ (lr & 7)) * 8];
            #pragma unroll
            for (int f = 0; f < 4; ++f) {
                int n = wc + f * 16 + lr;
                short8 bf8 = *(const short8*)&wb[n * 128 + (((s2 * 4 + lg) ^ lr) * 8)];
                acc[f] = __builtin_amdgcn_mfma_f32_16x16x32_bf16(a, bf8, acc[f], 0, 0, 0);
            }
        }
        bool phase_end = (h == 1);
        bool need_store = false;
        if (phase_end) {
            if (p == 0) {
                #pragma unroll
                for (int f = 0; f < 4; ++f) {
                    int col = wc + f * 16 + lr;
                    float bv = bo[col];
                    #pragma unroll
                    for (int rr = 0; rr < 4; ++rr) {
                        int row = r0 + wr + lg * 4 + rr;
                        x1[f][rr] = acc[f][rr] + bv + xg[(size_t)row * 256 + col];
                    }
                }
                need_store = true;
            } else if (p == 1) {
                #pragma unroll
                for (int f = 0; f < 4; ++f) {
                    int col = wc + f * 16 + lr;
                    float bv = bmlp[col];
                    #pragma unroll
                    for (int rr = 0; rr < 4; ++rr) {
                        int row = r0 + wr + lg * 4 + rr;
                        float v = x1[f][rr] + acc[f][rr] + bv;
                        x2[f][rr] = v;
                        xg[(size_t)row * 256 + col] = v;
                    }
                }
                need_store = (qg != nullptr);
            } else {
                int nc = p - 2;
                #pragma unroll
                for (int f = 0; f < 4; ++f) {
                    int col = wc + f * 16 + lr;
                    float bv = bqkv[nc * 256 + col];
                    int h2 = col >> 6, d = col & 63;
                    int bh = b * 4 + h2;
                    int t2 = (r0 & 2047) + wr + lg * 4;
                    if (nc == 2) {
                        short4_t pk;
                        #pragma unroll
                        for (int rr = 0; rr < 4; ++rr) pk[rr] = f2bf(acc[f][rr] + bv);
                        *(short4_t*)&vg[(size_t)bh * 131072 + (size_t)d * 2048 + t2] = pk;
                    } else {
                        short* dst = (nc == 0 ? qg : kg) + (size_t)bh * 131072 + (size_t)t2 * 64 + d;
                        #pragma unroll
                        for (int rr = 0; rr < 4; ++rr) dst[rr * 64] = f2bf(acc[f][rr] + bv);
                    }
                }
            }
            #pragma unroll
            for (int f = 0; f < 4; ++f) acc[f] = (f32x4){0.f, 0.f, 0.f, 0.f};
        }
        __builtin_amdgcn_s_barrier();          // all waves done with wl[h] and al
        if (need_store) {
            store_a(p == 0 ? x1 : x2);
            asm volatile("s_waitcnt lgkmcnt(0)" ::: "memory");
            __builtin_amdgcn_s_barrier();
        }
        if (s + 2 < nsteps) stage_w(s + 2);
    }
}

// ---------------- fp32-input GEMM for the head ------------------------------
__global__ __launch_bounds__(256) void gemm32_kernel(
    const float* __restrict__ A, const float* __restrict__ W,
    float* __restrict__ out, int M, int N, int K) {
    __shared__ short As[2][64][40];
    __shared__ short Bs[2][64][40];
    int tid = threadIdx.x, lane = tid & 63, wid = tid >> 6;
    int lg = lane >> 4, lr = lane & 15;
    int m0 = blockIdx.y * 64, n0 = blockIdx.x * 64;
    int wm = (wid >> 1) * 32, wn = (wid & 1) * 32;
    f32x4 acc[2][2] = {};
    int nt = K >> 5;
    float4 pa0, pa1;
    float pb[8];
    int ar = tid >> 3, ac4 = (tid & 7) * 4;
    int bn = tid & 63, bk8 = (tid >> 6) * 8;
    auto gload = [&](int k0) {
        pa0 = *(const float4*)(A + (size_t)(m0 + ar) * K + k0 + ac4);
        pa1 = *(const float4*)(A + (size_t)(m0 + ar + 32) * K + k0 + ac4);
        #pragma unroll
        for (int j = 0; j < 8; ++j) pb[j] = W[(size_t)(k0 + bk8 + j) * N + n0 + bn];
    };
    auto sstore = [&](int buf) {
        short4_t s0; s0.x=f2bf(pa0.x); s0.y=f2bf(pa0.y); s0.z=f2bf(pa0.z); s0.w=f2bf(pa0.w);
        *(short4_t*)&As[buf][ar][ac4] = s0;
        short4_t s1; s1.x=f2bf(pa1.x); s1.y=f2bf(pa1.y); s1.z=f2bf(pa1.z); s1.w=f2bf(pa1.w);
        *(short4_t*)&As[buf][ar + 32][ac4] = s1;
        short8 bb;
        #pragma unroll
        for (int j = 0; j < 8; ++j) bb[j] = f2bf(pb[j]);
        *(short8*)&Bs[buf][bn][bk8] = bb;
    };
    gload(0); sstore(0); __syncthreads();
    for (int t = 0; t < nt; ++t) {
        if (t + 1 < nt) gload((t + 1) << 5);
        int cur = t & 1;
        short8 af[2], bfr[2];
        af[0]  = *(const short8*)&As[cur][wm + lr][lg * 8];
        af[1]  = *(const short8*)&As[cur][wm + 16 + lr][lg * 8];
        bfr[0] = *(const short8*)&Bs[cur][wn + lr][lg * 8];
        bfr[1] = *(const short8*)&Bs[cur][wn + 16 + lr][lg * 8];
        #pragma unroll
        for (int mi = 0; mi < 2; ++mi)
            #pragma unroll
            for (int ni = 0; ni < 2; ++ni)
                acc[mi][ni] = __builtin_amdgcn_mfma_f32_16x16x32_bf16(
                    af[mi], bfr[ni], acc[mi][ni], 0, 0, 0);
        if (t + 1 < nt) sstore((t + 1) & 1);
        __syncthreads();
    }
    #pragma unroll
    for (int mi = 0; mi < 2; ++mi)
        #pragma unroll
        for (int ni = 0; ni < 2; ++ni) {
            int col = n0 + wn + ni * 16 + lr;
            #pragma unroll
            for (int r = 0; r < 4; ++r) {
                int row = m0 + wm + mi * 16 + lg * 4 + r;
                __builtin_nontemporal_store(acc[mi][ni][r], &out[(size_t)row * N + col]);
            }
        }
}

// ---------------------------------------------------------------------------
extern "C" void kernel_launch(void* const* d_in, const int* in_sizes, int n_in,
                              void* d_out, int out_size, void* d_ws, size_t ws_size,
                              hipStream_t stream) {
    (void)in_sizes; (void)n_in; (void)out_size; (void)ws_size;
    const int*   idx   = (const int*)  d_in[0];
    const float* tok   = (const float*)d_in[1];
    const float* pos   = (const float*)d_in[2];
    const float* Wqkv  = (const float*)d_in[3];
    const float* bqkv  = (const float*)d_in[4];
    const float* Wo    = (const float*)d_in[5];
    const float* bo    = (const float*)d_in[6];
    const float* Wfc   = (const float*)d_in[7];
    const float* bfc   = (const float*)d_in[8];
    const float* Wfp   = (const float*)d_in[9];
    const float* bfp   = (const float*)d_in[10];
    const float* Whead = (const float*)d_in[11];

    float* out = (float*)d_out;
    float* x   = (float*)d_ws;                    // fp32 [8192][256] (8 MB)

    // d_out scratch (16.78M floats; all consumed before head GEMM writes out):
    float* Opart  = out;                          // [2048 slabs][4096] = 8388608
    short* wqkv_t = (short*)(out + 8388608);      // [4][768][256]
    short* wo_t   = wqkv_t + 786432;              // [4][256][256]
    short* wfc_b  = wo_t + 262144;                // [4][256][1024]
    short* wfp_t  = wfc_b + 1048576;              // [4][256][1024]
    short* wmlp_t = wfp_t + 1048576;              // [4][256][256]
    float* bmlp   = (float*)(wmlp_t + 262144);    // [4][256]  ends 10093568
    float* rspart = out + 10093568;               // [2048 slabs][64] = 131072
    short* qgp = (short*)(out + 10485760);        // [16][2048][64]
    short* kgp = qgp + 2097152;
    short* vgp = kgp + 2097152;                   // [16][64][2048]
    short* xb0 = vgp + 2097152;                   // [8192][256] bf16 (embed out)

    // weight prep (deterministic, every call)
    convt_kernel<<<dim3(24, 8, 4), 256, 0, stream>>>(Wqkv, wqkv_t, 256, 768);
    convt_kernel<<<dim3(8, 8, 4), 256, 0, stream>>>(Wo, wo_t, 256, 256);
    convt_kernel<<<dim3(8, 32, 4), 256, 0, stream>>>(Wfp, wfp_t, 1024, 256);
    convc_kernel<<<512, 256, 0, stream>>>(Wfc, wfc_b);
    biasmlp_kernel<<<dim3(4, 4), 256, 0, stream>>>(bfc, Wfp, bfp, bmlp);
    gemmb_kernel<2><<<dim3(4, 4, 4), 256, 0, stream>>>(
        wfc_b, wfp_t, nullptr, nullptr, wmlp_t, nullptr, nullptr, nullptr,
        256, 256, 1024, 262144, 262144, 65536);

    embed_kernel<<<2048, 256, 0, stream>>>(idx, tok, pos, x, xb0);

    // qkv for layer 0
    gemmb_kernel<1><<<dim3(12, 128), 256, 0, stream>>>(
        xb0, wqkv_t, bqkv, nullptr, nullptr, qgp, kgp, vgp,
        8192, 768, 256, 0, 0, 0);

    for (int l = 0; l < 4; ++l) {
        attn_kernel<<<1280, 256, 0, stream>>>(qgp, kgp, vgp, Opart, rspart);
        bool last = (l == 3);
        layer_kernel<<<256, 512, 0, stream>>>(
            Opart, rspart, x,
            wo_t + l * 65536, bo + l * 256,
            wmlp_t + l * 65536, bmlp + l * 256,
            last ? nullptr : (wqkv_t + (l + 1) * 196608),
            last ? nullptr : (bqkv + (l + 1) * 768),
            last ? nullptr : qgp, last ? nullptr : kgp, last ? nullptr : vgp);
    }
    gemm32_kernel<<<dim3(32, 128), 256, 0, stream>>>(x, Whead, out, 8192, 2048, 256);
}

// Round 9
// 251.519 us; speedup vs baseline: 1.3567x; 1.0507x over previous
//
#include <hip/hip_runtime.h>

// GPT forward, MI355X gfx950. bf16 MFMA, fused MLP (no activation), max-free
// softmax (Q pre-scaled by 1/8 in weights), KV-split XCD-pinned attention,
// fused per-layer megakernel, bf16 head. B=4, T=2048, C=256, H=4, D=64, L=4.

typedef __attribute__((ext_vector_type(8))) short short8;
typedef __attribute__((ext_vector_type(4))) short short4_t;
typedef __attribute__((ext_vector_type(4))) float f32x4;

static __device__ __forceinline__ short f2bf(float f) {
    unsigned int u = __float_as_uint(f);
    unsigned int r = (u + 0x7FFFu + ((u >> 16) & 1u)) >> 16;  // RNE
    return (short)r;
}

static __device__ __forceinline__ void glds16(const void* g, void* l) {
    __builtin_amdgcn_global_load_lds(
        (const __attribute__((address_space(1))) unsigned int*)g,
        (__attribute__((address_space(3))) unsigned int*)l, 16, 0, 0);
}

// ---------------- embed: x = tok_emb[idx] + pos_emb; also bf16 copy ---------
__global__ __launch_bounds__(256) void embed_kernel(
    const int* __restrict__ idx, const float* __restrict__ tok,
    const float* __restrict__ pos, float* __restrict__ x, short* __restrict__ xb) {
    int i = (blockIdx.x * 256 + threadIdx.x) * 4;
    int row = i >> 8, c = i & 255, t = row & 2047;
    int tr = idx[row];
    float4 a = *(const float4*)(tok + (size_t)tr * 256 + c);
    float4 p = *(const float4*)(pos + (size_t)t * 256 + c);
    float4 o; o.x = a.x + p.x; o.y = a.y + p.y; o.z = a.z + p.z; o.w = a.w + p.w;
    *(float4*)(x + i) = o;
    short4_t s; s.x = f2bf(o.x); s.y = f2bf(o.y); s.z = f2bf(o.z); s.w = f2bf(o.w);
    *(short4_t*)(xb + i) = s;
}

// ---------------- consolidated weight prep -----------------------------------
// [0,768) Wqkv^T (Q-section x 1/8) | [768,1024) Wo^T | [1024,2048) Wfp^T |
// [2048,2560) Whead^T | [2560,3072) Wfc bf16 copy.
__global__ __launch_bounds__(256) void prepw_kernel(
    const float* __restrict__ Wqkv, const float* __restrict__ Wo,
    const float* __restrict__ Wfp, const float* __restrict__ Wfc,
    const float* __restrict__ Whead,
    short* __restrict__ wqkv_t, short* __restrict__ wo_t,
    short* __restrict__ wfp_t, short* __restrict__ wfc_b,
    short* __restrict__ whead_t) {
    __shared__ float tile[32][33];
    int b = blockIdx.x;
    if (b < 2560) {
        const float* src; short* dst; int R, C, c0, r0; bool qs = false;
        if (b < 768)       { int l = b / 192, r = b % 192;
            src = Wqkv + (size_t)l * 196608; dst = wqkv_t + (size_t)l * 196608;
            R = 256; C = 768; c0 = (r % 24) * 32; r0 = (r / 24) * 32; qs = true; }
        else if (b < 1024) { int t = b - 768; int l = t / 64, r = t % 64;
            src = Wo + (size_t)l * 65536; dst = wo_t + (size_t)l * 65536;
            R = 256; C = 256; c0 = (r % 8) * 32; r0 = (r / 8) * 32; }
        else if (b < 2048) { int t = b - 1024; int l = t / 256, r = t % 256;
            src = Wfp + (size_t)l * 262144; dst = wfp_t + (size_t)l * 262144;
            R = 1024; C = 256; c0 = (r % 8) * 32; r0 = (r / 8) * 32; }
        else               { int t = b - 2048;
            src = Whead; dst = whead_t;
            R = 256; C = 2048; c0 = (t % 64) * 32; r0 = (t / 64) * 32; }
        int tx = threadIdx.x & 31, ty = threadIdx.x >> 5;
        #pragma unroll
        for (int i = 0; i < 4; ++i)
            tile[ty + 8 * i][tx] = src[(size_t)(r0 + ty + 8 * i) * C + c0 + tx];
        __syncthreads();
        #pragma unroll
        for (int i = 0; i < 4; ++i) {
            int n = c0 + ty + 8 * i;
            float v = tile[tx][ty + 8 * i];
            if (qs && n < 256) v *= 0.125f;   // exact (2^-3)
            dst[(size_t)n * R + r0 + tx] = f2bf(v);
        }
    } else {
        int i = (b - 2560) * 2048 + threadIdx.x * 8;
        float4 a = *(const float4*)(Wfc + i);
        float4 b4 = *(const float4*)(Wfc + i + 4);
        short8 o; o[0]=f2bf(a.x); o[1]=f2bf(a.y); o[2]=f2bf(a.z); o[3]=f2bf(a.w);
        o[4]=f2bf(b4.x); o[5]=f2bf(b4.y); o[6]=f2bf(b4.z); o[7]=f2bf(b4.w);
        *(short8*)(wfc_b + i) = o;
    }
}

// bmlp = bfc@Wfp + bfp (y<4); y==4: bq_s = bqkv with Q-section x 1/8
__global__ __launch_bounds__(256) void biasmlp_kernel(
    const float* __restrict__ bfc, const float* __restrict__ wfp,
    const float* __restrict__ bfp, float* __restrict__ bmlp,
    const float* __restrict__ bqkv, float* __restrict__ bqs) {
    if (blockIdx.y == 4) {
        int l = blockIdx.x;
        for (int k = threadIdx.x; k < 768; k += 256)
            bqs[l * 768 + k] = bqkv[l * 768 + k] * (k < 256 ? 0.125f : 1.0f);
        return;
    }
    __shared__ float red[4][64];
    int l = blockIdx.x, ng = blockIdx.y;
    int n_in = threadIdx.x & 63, kk = threadIdx.x >> 6;
    int n = ng * 64 + n_in;
    const float* w = wfp + (size_t)l * 262144 + n;
    const float* bf = bfc + l * 1024;
    float s = 0.0f;
    #pragma unroll 4
    for (int k = kk * 256; k < kk * 256 + 256; ++k)
        s += bf[k] * w[(size_t)k * 256];
    red[kk][n_in] = s;
    __syncthreads();
    if (kk == 0)
        bmlp[l * 256 + n] = red[0][n_in] + red[1][n_in] + red[2][n_in] + red[3][n_in]
                            + bfp[l * 256 + n];
}

// ---------------- bf16 GEMM: A[M,K]bf16 @ Bt[N,K]bf16^T ----------------------
// MODE 0: plain fp32 out (nontemporal) — head GEMM.
// MODE 1: qkv split -> Qg/Kg bf16 [bh][t][64], Vg bf16 [bh][64][t].
// MODE 2: transposed bf16 out (Wmlp prep), batched via z.
template<int MODE>
__global__ __launch_bounds__(256) void gemmb_kernel(
    const short* __restrict__ A, const short* __restrict__ Bt,
    const float* __restrict__ bias, float* __restrict__ outf,
    short* __restrict__ outb,
    short* __restrict__ qg, short* __restrict__ kg, short* __restrict__ vg,
    int M, int N, int K, int sA, int sB, int sO) {
    __shared__ short Asb[3][4096];
    __shared__ short Bsb[3][4096];
    int tid = threadIdx.x, lane = tid & 63, wid = tid >> 6;
    int lg = lane >> 4, lr = lane & 15;
    int m0 = blockIdx.y * 64, n0 = blockIdx.x * 64;
    const short* Ab = A + (size_t)blockIdx.z * sA;
    const short* Bb = Bt + (size_t)blockIdx.z * sB;
    int wm = (wid >> 1) * 32, wn = (wid & 1) * 32;
    int srow = lane >> 3;
    int gc = (lane & 7) ^ (srow & 7);
    int nt = K >> 6;

    auto stage = [&](int t) {
        int buf = t - (t / 3) * 3;
        int k0 = t << 6;
        #pragma unroll
        for (int o2 = 0; o2 < 2; ++o2) {
            int o = wid * 2 + o2;
            glds16(Ab + (size_t)(m0 + o * 8 + srow) * K + k0 + gc * 8, &Asb[buf][o * 512]);
            glds16(Bb + (size_t)(n0 + o * 8 + srow) * K + k0 + gc * 8, &Bsb[buf][o * 512]);
        }
    };

    f32x4 acc[2][2] = {};
    stage(0);
    if (nt > 1) stage(1);

    for (int t = 0; t < nt; ++t) {
        if (t + 1 < nt) asm volatile("s_waitcnt vmcnt(4)" ::: "memory");
        else            asm volatile("s_waitcnt vmcnt(0)" ::: "memory");
        __builtin_amdgcn_s_barrier();
        if (t + 2 < nt) stage(t + 2);
        int buf = t - (t / 3) * 3;
        short8 af[2][2], bfr[2][2];
        #pragma unroll
        for (int mi = 0; mi < 2; ++mi) {
            int row = wm + mi * 16 + lr;
            #pragma unroll
            for (int h = 0; h < 2; ++h)
                af[mi][h] = *(const short8*)&Asb[buf][row * 64 + ((h * 4 + lg) ^ (lr & 7)) * 8];
        }
        #pragma unroll
        for (int ni = 0; ni < 2; ++ni) {
            int row = wn + ni * 16 + lr;
            #pragma unroll
            for (int h = 0; h < 2; ++h)
                bfr[ni][h] = *(const short8*)&Bsb[buf][row * 64 + ((h * 4 + lg) ^ (lr & 7)) * 8];
        }
        #pragma unroll
        for (int h = 0; h < 2; ++h)
            #pragma unroll
            for (int mi = 0; mi < 2; ++mi)
                #pragma unroll
                for (int ni = 0; ni < 2; ++ni)
                    acc[mi][ni] = __builtin_amdgcn_mfma_f32_16x16x32_bf16(
                        af[mi][h], bfr[ni][h], acc[mi][ni], 0, 0, 0);
    }

    #pragma unroll
    for (int mi = 0; mi < 2; ++mi) {
        #pragma unroll
        for (int ni = 0; ni < 2; ++ni) {
            int col = n0 + wn + ni * 16 + lr;
            if constexpr (MODE == 0) {
                #pragma unroll
                for (int r = 0; r < 4; ++r) {
                    int row = m0 + wm + mi * 16 + lg * 4 + r;
                    __builtin_nontemporal_store(acc[mi][ni][r], &outf[(size_t)row * N + col]);
                }
            } else if constexpr (MODE == 1) {
                float bv = bias[col];
                int sec = col >> 8, h = (col >> 6) & 3, d = col & 63;
                int rb = m0 + wm + mi * 16 + lg * 4;
                int t2 = rb & 2047, bh = ((rb >> 11) << 2) | h;
                if (sec == 2) {
                    short4_t pk;
                    #pragma unroll
                    for (int r = 0; r < 4; ++r) pk[r] = f2bf(acc[mi][ni][r] + bv);
                    *(short4_t*)&vg[(size_t)bh * 131072 + (size_t)d * 2048 + t2] = pk;
                } else {
                    short* dst = (sec == 0 ? qg : kg) + (size_t)bh * 131072 + (size_t)t2 * 64 + d;
                    #pragma unroll
                    for (int r = 0; r < 4; ++r) dst[r * 64] = f2bf(acc[mi][ni][r] + bv);
                }
            } else {
                #pragma unroll
                for (int r = 0; r < 4; ++r) {
                    int row = m0 + wm + mi * 16 + lg * 4 + r;
                    outb[(size_t)blockIdx.z * sO + (size_t)col * M + row] = f2bf(acc[mi][ni][r]);
                }
            }
        }
    }
}

// ---------------- causal flash attention, KV-split, XCD-pinned ---------------
// Q pre-scaled by 1/8; depth-1 prefetch, one barrier/iter; diag mask hoisted.
__global__ __launch_bounds__(256) void attn_kernel(
    const short* __restrict__ qg, const short* __restrict__ kg,
    const short* __restrict__ vg, float* __restrict__ Op, float* __restrict__ rp) {
    __shared__ short Kb[2][4096];
    __shared__ short Vb[2][4096];
    __shared__ short Ps[4][16][72];
    int g = blockIdx.x;
    int idx = g >> 3;
    int bh = (g & 7) * 2 + (idx / 80);
    int i = 79 - (idx % 80);
    int qt, s;
    if (i < 8)       { qt = i; s = 0; }
    else if (i < 24) { int j = i - 8;  qt = 8  + (j >> 1); s = j & 1; }
    else if (i < 48) { int j = i - 24; int q3 = j / 3; qt = 16 + q3; s = j - q3 * 3; }
    else             { int j = i - 48; qt = 24 + (j >> 2); s = j & 3; }
    int t0 = s * 8;
    int t1 = min(t0 + 8, qt + 1);
    int q0 = qt << 6;
    int tid = threadIdx.x, lane = tid & 63, wid = tid >> 6;
    int lg = lane >> 4, lr = lane & 15;
    const size_t base = (size_t)bh << 17;
    int srow = lane >> 3;
    int gc = (lane & 7) ^ (srow & 7);

    const short* qrow = qg + base + (size_t)(q0 + wid * 16 + lr) * 64;
    short8 qf0 = *(const short8*)(qrow + lg * 8);
    short8 qf1 = *(const short8*)(qrow + 32 + lg * 8);

    auto stage = [&](int t) {
        int buf = (t - t0) & 1;
        #pragma unroll
        for (int o2 = 0; o2 < 2; ++o2) {
            int o = wid * 2 + o2;
            glds16(kg + base + (size_t)(t * 64 + o * 8 + srow) * 64 + gc * 8, &Kb[buf][o * 512]);
            glds16(vg + base + (size_t)(o * 8 + srow) * 2048 + t * 64 + gc * 8, &Vb[buf][o * 512]);
        }
    };

    f32x4 o[4] = {};
    float rs = 0.0f;
    stage(t0);

    for (int j = t0; j < t1; ++j) {
        asm volatile("s_waitcnt vmcnt(0)" ::: "memory");
        __builtin_amdgcn_s_barrier();
        if (j + 1 < t1) stage(j + 1);        // into buf^1 (done being read)
        int buf = (j - t0) & 1;

        f32x4 sv[4];
        #pragma unroll
        for (int nf = 0; nf < 4; ++nf) {
            int row = nf * 16 + lr;
            short8 k0f = *(const short8*)&Kb[buf][row * 64 + ((0 + lg) ^ (lr & 7)) * 8];
            short8 k1f = *(const short8*)&Kb[buf][row * 64 + ((4 + lg) ^ (lr & 7)) * 8];
            f32x4 z = {};
            z = __builtin_amdgcn_mfma_f32_16x16x32_bf16(k0f, qf0, z, 0, 0, 0);
            z = __builtin_amdgcn_mfma_f32_16x16x32_bf16(k1f, qf1, z, 0, 0, 0);
            sv[nf] = z;
        }
        if (j == qt) {                        // diagonal tile: masked path
            #pragma unroll
            for (int nf = 0; nf < 4; ++nf) {
                short4_t p4;
                #pragma unroll
                for (int r = 0; r < 4; ++r) {
                    float v = sv[nf][r];
                    if (nf * 16 + lg * 4 + r > wid * 16 + lr) v = -3e38f;
                    float pe = __expf(v);
                    rs += pe;
                    p4[r] = f2bf(pe);
                }
                *(short4_t*)&Ps[wid][lr][nf * 16 + lg * 4] = p4;
            }
        } else {
            #pragma unroll
            for (int nf = 0; nf < 4; ++nf) {
                short4_t p4;
                #pragma unroll
                for (int r = 0; r < 4; ++r) {
                    float pe = __expf(sv[nf][r]);
                    rs += pe;
                    p4[r] = f2bf(pe);
                }
                *(short4_t*)&Ps[wid][lr][nf * 16 + lg * 4] = p4;
            }
        }
        short8 pf0 = *(const short8*)&Ps[wid][lr][lg * 8];
        short8 pf1 = *(const short8*)&Ps[wid][lr][32 + lg * 8];
        #pragma unroll
        for (int df = 0; df < 4; ++df) {
            int row = df * 16 + lr;
            short8 v0 = *(const short8*)&Vb[buf][row * 64 + ((0 + lg) ^ (lr & 7)) * 8];
            short8 v1 = *(const short8*)&Vb[buf][row * 64 + ((4 + lg) ^ (lr & 7)) * 8];
            o[df] = __builtin_amdgcn_mfma_f32_16x16x32_bf16(pf0, v0, o[df], 0, 0, 0);
            o[df] = __builtin_amdgcn_mfma_f32_16x16x32_bf16(pf1, v1, o[df], 0, 0, 0);
        }
    }

    rs += __shfl_xor(rs, 16);
    rs += __shfl_xor(rs, 32);

    int slab = (bh * 32 + qt) * 4 + s;
    float* ob = Op + (size_t)slab * 4096;
    #pragma unroll
    for (int df = 0; df < 4; ++df)
        #pragma unroll
        for (int r = 0; r < 4; ++r)
            ob[(wid * 16 + lg * 4 + r) * 64 + df * 16 + lr] = o[df][r];
    if (lane < 16) rp[slab * 64 + wid * 16 + lane] = rs;
}

// ---------------- fused layer: combine + proj + MLP + next qkv ---------------
__global__ __launch_bounds__(512) void layer_kernel(
    const float* __restrict__ Op, const float* __restrict__ rp,
    float* __restrict__ xg, short* __restrict__ xh,
    const short* __restrict__ wo, const float* __restrict__ bo,
    const short* __restrict__ wmlp, const float* __restrict__ bmlp,
    const short* __restrict__ wqkv, const float* __restrict__ bqkv,
    short* __restrict__ qg, short* __restrict__ kg, short* __restrict__ vg) {
    __shared__ short al[4][32][64];      // 16 KB (A operand, swizzled)
    __shared__ short wl[2][32768];       // 2 x 64 KB (weight half-K buffers)
    int tid = threadIdx.x, lane = tid & 63, wid = tid >> 6;
    int lg = (lane >> 4) & 3, lr = lane & 15;
    int r0 = blockIdx.x * 32;
    int b = r0 >> 11, qt = (r0 & 2047) >> 6;
    int rowIn0 = r0 & 32;
    int ns = (qt >> 3) + 1;
    int wr = (wid & 1) * 16, wc = (wid >> 1) * 64;

    const short* wlist[5];
    wlist[0] = wo; wlist[1] = wmlp; wlist[2] = wqkv;
    wlist[3] = wqkv ? wqkv + 65536 : wo; wlist[4] = wqkv ? wqkv + 131072 : wo;
    int nsteps = qg ? 10 : 4;

    // ---- combine partials -> y bf16 in al ----
    {
        int row = tid >> 4, seg = tid & 15;
        int h = seg >> 2, d0 = (seg & 3) * 16;
        int slab0 = ((b * 4 + h) * 32 + qt) * 4;
        float a[16] = {};
        float rtot = 0.0f;
        for (int s = 0; s < ns; ++s) {
            const float* op = Op + (size_t)(slab0 + s) * 4096 + (rowIn0 + row) * 64 + d0;
            #pragma unroll
            for (int i2 = 0; i2 < 4; ++i2) {
                float4 v = *(const float4*)(op + i2 * 4);
                a[i2*4+0] += v.x; a[i2*4+1] += v.y; a[i2*4+2] += v.z; a[i2*4+3] += v.w;
            }
            rtot += rp[(slab0 + s) * 64 + rowIn0 + row];
        }
        float inv = 1.0f / rtot;
        short8 o0, o1;
        #pragma unroll
        for (int i2 = 0; i2 < 8; ++i2) { o0[i2] = f2bf(a[i2] * inv); o1[i2] = f2bf(a[8 + i2] * inv); }
        int c0 = d0 >> 3;
        *(short8*)&al[h][row][((c0) ^ (row & 7)) * 8] = o0;
        *(short8*)&al[h][row][((c0 + 1) ^ (row & 7)) * 8] = o1;
    }

    auto stage_w = [&](int s) {
        const short* wt = wlist[s >> 1];
        int h = s & 1;
        short* dst = wl[h];
        int n_l = lane >> 4, cl = lane & 15;
        #pragma unroll
        for (int c4 = 0; c4 < 8; ++c4) {
            int n0 = wid * 32 + c4 * 4;
            int n = n0 + n_l;
            glds16(wt + (size_t)n * 256 + h * 128 + (cl ^ (n & 15)) * 8,
                   dst + n0 * 128);
        }
    };
    auto store_a = [&](f32x4* v) {
        #pragma unroll
        for (int f = 0; f < 4; ++f) {
            int col = wc + f * 16 + lr;
            int h2 = col >> 6, ch = (col & 63) >> 3, pos = col & 7;
            #pragma unroll
            for (int rr = 0; rr < 4; ++rr) {
                int row = wr + lg * 4 + rr;
                al[h2][row][(ch ^ (row & 7)) * 8 + pos] = f2bf(v[f][rr]);
            }
        }
    };

    stage_w(0);
    stage_w(1);
    asm volatile("s_waitcnt lgkmcnt(0)" ::: "memory");
    __builtin_amdgcn_s_barrier();

    f32x4 acc[4] = {};
    f32x4 x1[4], x2[4];

    for (int s = 0; s < nsteps; ++s) {
        if (s == nsteps - 1) asm volatile("s_waitcnt vmcnt(0)" ::: "memory");
        else                 asm volatile("s_waitcnt vmcnt(8)" ::: "memory");
        __builtin_amdgcn_s_barrier();
        int h = s & 1, p = s >> 1;
        const short* wb = wl[h];
        #pragma unroll
        for (int s2 = 0; s2 < 4; ++s2) {
            int ksg = h * 4 + s2;
            short8 a = *(const short8*)&al[ksg >> 1][wr + lr][((((ksg & 1) << 2) + lg) ^ (lr & 7)) * 8];
            #pragma unroll
            for (int f = 0; f < 4; ++f) {
                int n = wc + f * 16 + lr;
                short8 bf8 = *(const short8*)&wb[n * 128 + (((s2 * 4 + lg) ^ lr) * 8)];
                acc[f] = __builtin_amdgcn_mfma_f32_16x16x32_bf16(a, bf8, acc[f], 0, 0, 0);
            }
        }
        bool phase_end = (h == 1);
        bool need_store = false;
        if (phase_end) {
            if (p == 0) {
                #pragma unroll
                for (int f = 0; f < 4; ++f) {
                    int col = wc + f * 16 + lr;
                    float bv = bo[col];
                    #pragma unroll
                    for (int rr = 0; rr < 4; ++rr) {
                        int row = r0 + wr + lg * 4 + rr;
                        x1[f][rr] = acc[f][rr] + bv + xg[(size_t)row * 256 + col];
                    }
                }
                need_store = true;
            } else if (p == 1) {
                #pragma unroll
                for (int f = 0; f < 4; ++f) {
                    int col = wc + f * 16 + lr;
                    float bv = bmlp[col];
                    #pragma unroll
                    for (int rr = 0; rr < 4; ++rr) {
                        int row = r0 + wr + lg * 4 + rr;
                        float v = x1[f][rr] + acc[f][rr] + bv;
                        x2[f][rr] = v;
                        if (qg) xg[(size_t)row * 256 + col] = v;
                        else    xh[(size_t)row * 256 + col] = f2bf(v);
                    }
                }
                need_store = (qg != nullptr);
            } else {
                int nc = p - 2;
                #pragma unroll
                for (int f = 0; f < 4; ++f) {
                    int col = wc + f * 16 + lr;
                    float bv = bqkv[nc * 256 + col];
                    int h2 = col >> 6, d = col & 63;
                    int bh = b * 4 + h2;
                    int t2 = (r0 & 2047) + wr + lg * 4;
                    if (nc == 2) {
                        short4_t pk;
                        #pragma unroll
                        for (int rr = 0; rr < 4; ++rr) pk[rr] = f2bf(acc[f][rr] + bv);
                        *(short4_t*)&vg[(size_t)bh * 131072 + (size_t)d * 2048 + t2] = pk;
                    } else {
                        short* dst = (nc == 0 ? qg : kg) + (size_t)bh * 131072 + (size_t)t2 * 64 + d;
                        #pragma unroll
                        for (int rr = 0; rr < 4; ++rr) dst[rr * 64] = f2bf(acc[f][rr] + bv);
                    }
                }
            }
            #pragma unroll
            for (int f = 0; f < 4; ++f) acc[f] = (f32x4){0.f, 0.f, 0.f, 0.f};
        }
        __builtin_amdgcn_s_barrier();
        if (need_store) {
            store_a(p == 0 ? x1 : x2);
            asm volatile("s_waitcnt lgkmcnt(0)" ::: "memory");
            __builtin_amdgcn_s_barrier();
        }
        if (s + 2 < nsteps) stage_w(s + 2);
    }
}

// ---------------------------------------------------------------------------
extern "C" void kernel_launch(void* const* d_in, const int* in_sizes, int n_in,
                              void* d_out, int out_size, void* d_ws, size_t ws_size,
                              hipStream_t stream) {
    (void)in_sizes; (void)n_in; (void)out_size; (void)ws_size;
    const int*   idx   = (const int*)  d_in[0];
    const float* tok   = (const float*)d_in[1];
    const float* pos   = (const float*)d_in[2];
    const float* Wqkv  = (const float*)d_in[3];
    const float* bqkv  = (const float*)d_in[4];
    const float* Wo    = (const float*)d_in[5];
    const float* bo    = (const float*)d_in[6];
    const float* Wfc   = (const float*)d_in[7];
    const float* bfc   = (const float*)d_in[8];
    const float* Wfp   = (const float*)d_in[9];
    const float* bfp   = (const float*)d_in[10];
    const float* Whead = (const float*)d_in[11];

    float* out = (float*)d_out;
    float* ws  = (float*)d_ws;

    // d_ws layout (>=268 MB; head reads live here, away from d_out it writes):
    float* x       = ws;                          // [8192][256] fp32
    short* xb3     = (short*)(ws + 2097152);      // [8192][256] bf16 (head A)
    short* whead_t = (short*)(ws + 3145728);      // [2048][256] bf16 (head B)
    float* bq_s    = ws + 3407872;                // [4][768] scaled qkv bias

    // d_out scratch (all consumed before head GEMM writes out):
    float* Opart  = out;                          // [2048 slabs][4096]
    short* wqkv_t = (short*)(out + 8388608);      // [4][768][256]
    short* wo_t   = wqkv_t + 786432;              // [4][256][256]
    short* wfc_b  = wo_t + 262144;                // [4][256][1024]
    short* wfp_t  = wfc_b + 1048576;              // [4][256][1024]
    short* wmlp_t = wfp_t + 1048576;              // [4][256][256]
    float* bmlp   = (float*)(wmlp_t + 262144);    // [4][256]
    float* rspart = out + 10093568;               // [2048 slabs][64]
    short* qgp = (short*)(out + 10485760);        // [16][2048][64]
    short* kgp = qgp + 2097152;
    short* vgp = kgp + 2097152;                   // [16][64][2048]
    short* xb0 = vgp + 2097152;                   // [8192][256] bf16 (embed out)

    // weight prep (deterministic, every call)
    prepw_kernel<<<3072, 256, 0, stream>>>(
        Wqkv, Wo, Wfp, Wfc, Whead, wqkv_t, wo_t, wfp_t, wfc_b, whead_t);
    biasmlp_kernel<<<dim3(4, 5), 256, 0, stream>>>(bfc, Wfp, bfp, bmlp, bqkv, bq_s);
    gemmb_kernel<2><<<dim3(4, 4, 4), 256, 0, stream>>>(
        wfc_b, wfp_t, nullptr, nullptr, wmlp_t, nullptr, nullptr, nullptr,
        256, 256, 1024, 262144, 262144, 65536);

    embed_kernel<<<2048, 256, 0, stream>>>(idx, tok, pos, x, xb0);

    // qkv for layer 0 (Q pre-scaled via wqkv_t/bq_s)
    gemmb_kernel<1><<<dim3(12, 128), 256, 0, stream>>>(
        xb0, wqkv_t, bq_s, nullptr, nullptr, qgp, kgp, vgp,
        8192, 768, 256, 0, 0, 0);

    for (int l = 0; l < 4; ++l) {
        attn_kernel<<<1280, 256, 0, stream>>>(qgp, kgp, vgp, Opart, rspart);
        bool last = (l == 3);
        layer_kernel<<<256, 512, 0, stream>>>(
            Opart, rspart, x, xb3,
            wo_t + l * 65536, bo + l * 256,
            wmlp_t + l * 65536, bmlp + l * 256,
            last ? nullptr : (wqkv_t + (l + 1) * 196608),
            last ? nullptr : (bq_s + (l + 1) * 768),
            last ? nullptr : qgp, last ? nullptr : kgp, last ? nullptr : vgp);
    }
    // head: logits = xb3 @ whead_t^T (bf16 pipeline, fp32 out)
    gemmb_kernel<0><<<dim3(32, 128), 256, 0, stream>>>(
        xb3, whead_t, nullptr, out, nullptr, nullptr, nullptr, nullptr,
        8192, 2048, 256, 0, 0, 0);
}